// Round 2
// baseline (267.326 us; speedup 1.0000x reference)
//
#include <hip/hip_runtime.h>
#include <hip/hip_fp16.h>
#include <math.h>

#define NN 50000
#define NE 800000
#define RAWSTRIDE 96           // raw row stride (u16 col slots) per node
#define SB 782                 // scatter blocks: ceil(NE/4/256)
#define G1B 782                // ceil(NN/64) gemm row-blocks

using bf8v = __attribute__((ext_vector_type(8))) short;   // 8 bf16 (4 VGPRs)
using f4v  = __attribute__((ext_vector_type(4))) float;   // 4 fp32 acc

__device__ inline unsigned short f2bf(float f) {          // RNE f32->bf16
    unsigned int u = __float_as_uint(f);
    u += 0x7FFFu + ((u >> 16) & 1u);
    return (unsigned short)(u >> 16);
}
__device__ inline float bflo(unsigned int d) { return __uint_as_float(d << 16); }
__device__ inline float bfhi(unsigned int d) { return __uint_as_float(d & 0xFFFF0000u); }

// ---------------- MFMA bf16 GEMM body (layers 1-2): out_bf16[Nx128] = A[Nx128] @ W[128x128] ----

template <bool A_FP32>
__device__ __forceinline__ void gemm128_body(const void* __restrict__ Ain,
                                             const float* __restrict__ W,
                                             unsigned short* __restrict__ out,
                                             int bx, char* shc) {
    unsigned short* Wt = (unsigned short*)shc;            // [128][136] bf16
    unsigned short* Dt = (unsigned short*)(shc + 128 * 136 * 2);  // [64][136] bf16
    const int t = threadIdx.x;
    const int row0 = bx * 64;

    {
        int n = t & 127;
        int kbase = (t >> 7) * 4;
        for (int kk = kbase; kk < 128; kk += 8) {
            float w0 = W[(kk + 0) * 128 + n];
            float w1 = W[(kk + 1) * 128 + n];
            float w2 = W[(kk + 2) * 128 + n];
            float w3 = W[(kk + 3) * 128 + n];
            unsigned int p0 = (unsigned int)f2bf(w0) | ((unsigned int)f2bf(w1) << 16);
            unsigned int p1 = (unsigned int)f2bf(w2) | ((unsigned int)f2bf(w3) << 16);
            *(unsigned int*)&Wt[n * 136 + kk]     = p0;
            *(unsigned int*)&Wt[n * 136 + kk + 2] = p1;
        }
    }
    __syncthreads();

    const int wave = t >> 6;
    const int lane = t & 63;
    const int m16  = lane & 15;
    const int quad = lane >> 4;
    const int arow = row0 + wave * 16 + m16;
    const int arowc = (arow < NN) ? arow : 0;

    f4v acc[8];
    #pragma unroll
    for (int i = 0; i < 8; ++i) acc[i] = (f4v)(0.0f);

    #pragma unroll
    for (int k0 = 0; k0 < 128; k0 += 32) {
        bf8v afrag;
        if (A_FP32) {
            const float* A = (const float*)Ain;
            const float4* ap = (const float4*)(A + (size_t)arowc * 128 + k0 + quad * 8);
            float4 a0 = ap[0], a1 = ap[1];
            afrag[0] = (short)f2bf(a0.x); afrag[1] = (short)f2bf(a0.y);
            afrag[2] = (short)f2bf(a0.z); afrag[3] = (short)f2bf(a0.w);
            afrag[4] = (short)f2bf(a1.x); afrag[5] = (short)f2bf(a1.y);
            afrag[6] = (short)f2bf(a1.z); afrag[7] = (short)f2bf(a1.w);
        } else {
            const unsigned short* A = (const unsigned short*)Ain;
            afrag = *(const bf8v*)(A + (size_t)arowc * 128 + k0 + quad * 8);
        }
        #pragma unroll
        for (int nt = 0; nt < 8; ++nt) {
            bf8v bfrag = *(const bf8v*)&Wt[(nt * 16 + m16) * 136 + k0 + quad * 8];
            acc[nt] = __builtin_amdgcn_mfma_f32_16x16x32_bf16(afrag, bfrag, acc[nt], 0, 0, 0);
        }
    }

    #pragma unroll
    for (int nt = 0; nt < 8; ++nt) {
        #pragma unroll
        for (int r = 0; r < 4; ++r) {
            Dt[(wave * 16 + quad * 4 + r) * 136 + nt * 16 + m16] = f2bf(acc[nt][r]);
        }
    }
    __syncthreads();

    {
        int r = t >> 2;
        int c = t & 3;
        int gr = row0 + r;
        if (gr < NN) {
            const uint4* s = (const uint4*)&Dt[r * 136] + c * 4;
            uint4* d = (uint4*)(out + (size_t)gr * 128) + c * 4;
            d[0] = s[0]; d[1] = s[1]; d[2] = s[2]; d[3] = s[3];
        }
    }
}

// ---------------- fused: direct CSR scatter (782 blocks) + layer-1 GEMM (782 blocks) ----------
// Scatter: p = atomicAdd(cnt[dst]); raw[dst*96+p] = src. Device-scope atomics, uniform over
// a 200KB counter array; replaces the old 2-phase bucket sort (bin+sortb) entirely.

__global__ __launch_bounds__(256) void scat_g1_kernel(const int* __restrict__ src,
                                                      const int* __restrict__ dst,
                                                      int* __restrict__ cnt_g,
                                                      unsigned short* __restrict__ raw,
                                                      const float* __restrict__ x,
                                                      const float* __restrict__ W1,
                                                      unsigned short* __restrict__ hb) {
    __shared__ __align__(16) char sh[52224];
    if (blockIdx.x < SB) {
        int idx = blockIdx.x * 256 + threadIdx.x;
        int e0 = idx * 4;
        if (e0 < NE) {
            int4 s4 = *(const int4*)(src + e0);
            int4 d4 = *(const int4*)(dst + e0);
            int p;
            p = atomicAdd(cnt_g + d4.x, 1);
            if (p < RAWSTRIDE) raw[(size_t)d4.x * RAWSTRIDE + p] = (unsigned short)s4.x;
            p = atomicAdd(cnt_g + d4.y, 1);
            if (p < RAWSTRIDE) raw[(size_t)d4.y * RAWSTRIDE + p] = (unsigned short)s4.y;
            p = atomicAdd(cnt_g + d4.z, 1);
            if (p < RAWSTRIDE) raw[(size_t)d4.z * RAWSTRIDE + p] = (unsigned short)s4.z;
            p = atomicAdd(cnt_g + d4.w, 1);
            if (p < RAWSTRIDE) raw[(size_t)d4.w * RAWSTRIDE + p] = (unsigned short)s4.w;
        }
    } else {
        gemm128_body<true>(x, W1, hb, blockIdx.x - SB, sh);
    }
}

// standalone gemm (layer 2)
__global__ __launch_bounds__(256) void mfma_gemm_kernel(const unsigned short* __restrict__ Ain,
                                                        const float* __restrict__ W,
                                                        unsigned short* __restrict__ out) {
    __shared__ __align__(16) char sh[52224];
    gemm128_body<false>(Ain, W, out, blockIdx.x, sh);
}

// ---------------- bf16 pull aggregation (layers 1-2), on-the-fly weights ----------------
// 16 lanes/group (uint4 = 8 bf16 feats), 16 groups/block, 8-edge unroll.
// weight = rsqrt(1+cnt[wid]) * rsqrt(1+cnt[col]); cnt table is 200KB, L2-resident;
// trans-pipe rsqrts hide under the ~5x memory slack of the gather loop.

template <bool RELU>
__global__ __launch_bounds__(256) void agg_bf16_kernel(const unsigned short* __restrict__ hin,
                                                       const unsigned short* __restrict__ raw,
                                                       const int* __restrict__ cnt_g,
                                                       const float* __restrict__ bias,
                                                       unsigned short* __restrict__ outb) {
    const int t = threadIdx.x;
    const int group = t >> 4;
    const int lane  = t & 15;
    const int wid = blockIdx.x * 16 + group;
    if (wid >= NN) return;

    const int cn = cnt_g[wid];
    int c = (cn > RAWSTRIDE) ? RAWSTRIDE : cn;
    const float diw = rsqrtf(1.0f + (float)cn);
    const unsigned short* rrow = raw + (size_t)wid * RAWSTRIDE;
    const uint4* hv = (const uint4*)hin;

    float acc[8];
    {   // self loop, fp32 weight
        uint4 g = hv[(size_t)wid * 16 + lane];
        float ws = diw * diw;
        acc[0] = ws * bflo(g.x); acc[1] = ws * bfhi(g.x);
        acc[2] = ws * bflo(g.y); acc[3] = ws * bfhi(g.y);
        acc[4] = ws * bflo(g.z); acc[5] = ws * bfhi(g.z);
        acc[6] = ws * bflo(g.w); acc[7] = ws * bfhi(g.w);
    }

    #define ACCUM(G, W_) \
        acc[0] += W_ * bflo(G.x); acc[1] += W_ * bfhi(G.x); \
        acc[2] += W_ * bflo(G.y); acc[3] += W_ * bfhi(G.y); \
        acc[4] += W_ * bflo(G.z); acc[5] += W_ * bfhi(G.z); \
        acc[6] += W_ * bflo(G.w); acc[7] += W_ * bfhi(G.w);
    #define EW(CI) (diw * rsqrtf(1.0f + (float)cnt_g[CI]))

    const int cfull = c & ~7;
    for (int e = 0; e < cfull; e += 8) {
        uint4 q = *(const uint4*)(rrow + e);
        int c0 = q.x & 0xFFFFu, c1 = q.x >> 16;
        int c2 = q.y & 0xFFFFu, c3 = q.y >> 16;
        int c4 = q.z & 0xFFFFu, c5 = q.z >> 16;
        int c6 = q.w & 0xFFFFu, c7 = q.w >> 16;
        float w0 = EW(c0), w1 = EW(c1), w2 = EW(c2), w3 = EW(c3);
        float w4 = EW(c4), w5 = EW(c5), w6 = EW(c6), w7 = EW(c7);
        uint4 g0 = hv[(size_t)c0 * 16 + lane];
        uint4 g1 = hv[(size_t)c1 * 16 + lane];
        uint4 g2 = hv[(size_t)c2 * 16 + lane];
        uint4 g3 = hv[(size_t)c3 * 16 + lane];
        uint4 g4 = hv[(size_t)c4 * 16 + lane];
        uint4 g5 = hv[(size_t)c5 * 16 + lane];
        uint4 g6 = hv[(size_t)c6 * 16 + lane];
        uint4 g7 = hv[(size_t)c7 * 16 + lane];
        ACCUM(g0, w0) ACCUM(g1, w1) ACCUM(g2, w2) ACCUM(g3, w3)
        ACCUM(g4, w4) ACCUM(g5, w5) ACCUM(g6, w6) ACCUM(g7, w7)
    }
    if (c & 7) {                       // predicated tail chunk
        int e = cfull, rem = c - e;    // 1..7
        uint4 q = *(const uint4*)(rrow + e);
        int c0 = q.x & 0xFFFFu, c1 = q.x >> 16;
        int c2 = q.y & 0xFFFFu, c3 = q.y >> 16;
        int c4 = q.z & 0xFFFFu, c5 = q.z >> 16;
        int c6 = q.w & 0xFFFFu, c7 = q.w >> 16;
        if (rem <= 1) c1 = 0; if (rem <= 2) c2 = 0; if (rem <= 3) c3 = 0;
        if (rem <= 4) c4 = 0; if (rem <= 5) c5 = 0; if (rem <= 6) c6 = 0;
        c7 = 0;
        float w0 = EW(c0);
        float w1 = (rem > 1) ? EW(c1) : 0.f;
        float w2 = (rem > 2) ? EW(c2) : 0.f;
        float w3 = (rem > 3) ? EW(c3) : 0.f;
        float w4 = (rem > 4) ? EW(c4) : 0.f;
        float w5 = (rem > 5) ? EW(c5) : 0.f;
        float w6 = (rem > 6) ? EW(c6) : 0.f;
        float w7 = 0.f;
        uint4 g0 = hv[(size_t)c0 * 16 + lane];
        uint4 g1 = hv[(size_t)c1 * 16 + lane];
        uint4 g2 = hv[(size_t)c2 * 16 + lane];
        uint4 g3 = hv[(size_t)c3 * 16 + lane];
        uint4 g4 = hv[(size_t)c4 * 16 + lane];
        uint4 g5 = hv[(size_t)c5 * 16 + lane];
        uint4 g6 = hv[(size_t)c6 * 16 + lane];
        uint4 g7 = hv[(size_t)c7 * 16 + lane];
        ACCUM(g0, w0) ACCUM(g1, w1) ACCUM(g2, w2) ACCUM(g3, w3)
        ACCUM(g4, w4) ACCUM(g5, w5) ACCUM(g6, w6) ACCUM(g7, w7)
    }
    #undef EW
    #undef ACCUM

    const float4* bp = (const float4*)bias;
    float4 b0 = bp[lane * 2], b1 = bp[lane * 2 + 1];
    acc[0] += b0.x; acc[1] += b0.y; acc[2] += b0.z; acc[3] += b0.w;
    acc[4] += b1.x; acc[5] += b1.y; acc[6] += b1.z; acc[7] += b1.w;
    if (RELU) {
        #pragma unroll
        for (int j = 0; j < 8; ++j) acc[j] = fmaxf(acc[j], 0.f);
    }
    uint4 o;
    o.x = (unsigned int)f2bf(acc[0]) | ((unsigned int)f2bf(acc[1]) << 16);
    o.y = (unsigned int)f2bf(acc[2]) | ((unsigned int)f2bf(acc[3]) << 16);
    o.z = (unsigned int)f2bf(acc[4]) | ((unsigned int)f2bf(acc[5]) << 16);
    o.w = (unsigned int)f2bf(acc[6]) | ((unsigned int)f2bf(acc[7]) << 16);
    ((uint4*)(outb + (size_t)wid * 128))[lane] = o;
}

// ---------------- layer-3 GEMM (fp32 compute, bf16 in, bf16 out): h3 = z2 @ W3 ----------------

__global__ __launch_bounds__(256) void gemm3_kernel(const unsigned short* __restrict__ Ab,
                                                    const float* __restrict__ W,
                                                    unsigned short* __restrict__ outh) {
    constexpr int CG = 16;
    constexpr int RPT = 4;
    constexpr int ROWS = 64;
    constexpr int LD = 132;
    __shared__ float lds[ROWS * LD];
    const int t = threadIdx.x;
    const int row0 = blockIdx.x * ROWS;

    #pragma unroll
    for (int j = 0; j < ROWS / 8; ++j) {
        int idx4 = j * 256 + t;
        int r = idx4 >> 5, c4 = idx4 & 31;
        int gr = row0 + r;
        uint2 u = make_uint2(0u, 0u);
        if (gr < NN) u = ((const uint2*)(Ab + (size_t)gr * 128))[c4];
        float4 v;
        v.x = bflo(u.x); v.y = bfhi(u.x); v.z = bflo(u.y); v.w = bfhi(u.y);
        ((float4*)(lds + r * LD))[c4] = v;
    }
    __syncthreads();

    const int cg = t % CG;
    const int rt = t / CG;
    const float4* Wv = (const float4*)W;
    float4 acc[RPT];
    #pragma unroll
    for (int i = 0; i < RPT; ++i) acc[i] = make_float4(0.f, 0.f, 0.f, 0.f);

    for (int k0 = 0; k0 < 128; k0 += 4) {
        float4 w0 = Wv[(k0 + 0) * CG + cg];
        float4 w1 = Wv[(k0 + 1) * CG + cg];
        float4 w2 = Wv[(k0 + 2) * CG + cg];
        float4 w3 = Wv[(k0 + 3) * CG + cg];
        #pragma unroll
        for (int i = 0; i < RPT; ++i) {
            const float* lr = lds + (rt * RPT + i) * LD;
            float4 a = ((const float4*)lr)[k0 >> 2];
            acc[i].x += a.x * w0.x + a.y * w1.x + a.z * w2.x + a.w * w3.x;
            acc[i].y += a.x * w0.y + a.y * w1.y + a.z * w2.y + a.w * w3.y;
            acc[i].z += a.x * w0.z + a.y * w1.z + a.z * w2.z + a.w * w3.z;
            acc[i].w += a.x * w0.w + a.y * w1.w + a.z * w2.w + a.w * w3.w;
        }
    }

    #pragma unroll
    for (int i = 0; i < RPT; ++i) {
        int gr = row0 + rt * RPT + i;
        if (gr < NN) {
            uint2 o;
            o.x = (unsigned int)f2bf(acc[i].x) | ((unsigned int)f2bf(acc[i].y) << 16);
            o.y = (unsigned int)f2bf(acc[i].z) | ((unsigned int)f2bf(acc[i].w) << 16);
            ((uint2*)(outh + (size_t)gr * 64))[cg] = o;
        }
    }
}

// ---------------- layer-3 aggregation: bf16 gather (128B rows) -> fp32 out ----------------

__global__ __launch_bounds__(256) void agg3_kernel(const unsigned short* __restrict__ hin,
                                                   const unsigned short* __restrict__ raw,
                                                   const int* __restrict__ cnt_g,
                                                   const float* __restrict__ bias,
                                                   float* __restrict__ out) {
    const int t = threadIdx.x;
    const int group = t >> 3;
    const int lane  = t & 7;
    const int wid = blockIdx.x * 32 + group;
    if (wid >= NN) return;

    const int cn = cnt_g[wid];
    int c = (cn > RAWSTRIDE) ? RAWSTRIDE : cn;
    const float diw = rsqrtf(1.0f + (float)cn);
    const unsigned short* rrow = raw + (size_t)wid * RAWSTRIDE;
    const uint4* hv = (const uint4*)hin;      // 8 uint4 per 64-feat bf16 row

    float acc[8];
    {   // self loop
        uint4 g = hv[(size_t)wid * 8 + lane];
        float ws = diw * diw;
        acc[0] = ws * bflo(g.x); acc[1] = ws * bfhi(g.x);
        acc[2] = ws * bflo(g.y); acc[3] = ws * bfhi(g.y);
        acc[4] = ws * bflo(g.z); acc[5] = ws * bfhi(g.z);
        acc[6] = ws * bflo(g.w); acc[7] = ws * bfhi(g.w);
    }

    #define ACCUM(G, W_) \
        acc[0] += W_ * bflo(G.x); acc[1] += W_ * bfhi(G.x); \
        acc[2] += W_ * bflo(G.y); acc[3] += W_ * bfhi(G.y); \
        acc[4] += W_ * bflo(G.z); acc[5] += W_ * bfhi(G.z); \
        acc[6] += W_ * bflo(G.w); acc[7] += W_ * bfhi(G.w);
    #define EW(CI) (diw * rsqrtf(1.0f + (float)cnt_g[CI]))

    const int cfull = c & ~7;
    for (int e = 0; e < cfull; e += 8) {
        uint4 q = *(const uint4*)(rrow + e);
        int c0 = q.x & 0xFFFFu, c1 = q.x >> 16;
        int c2 = q.y & 0xFFFFu, c3 = q.y >> 16;
        int c4 = q.z & 0xFFFFu, c5 = q.z >> 16;
        int c6 = q.w & 0xFFFFu, c7 = q.w >> 16;
        float w0 = EW(c0), w1 = EW(c1), w2 = EW(c2), w3 = EW(c3);
        float w4 = EW(c4), w5 = EW(c5), w6 = EW(c6), w7 = EW(c7);
        uint4 g0 = hv[(size_t)c0 * 8 + lane];
        uint4 g1 = hv[(size_t)c1 * 8 + lane];
        uint4 g2 = hv[(size_t)c2 * 8 + lane];
        uint4 g3 = hv[(size_t)c3 * 8 + lane];
        uint4 g4 = hv[(size_t)c4 * 8 + lane];
        uint4 g5 = hv[(size_t)c5 * 8 + lane];
        uint4 g6 = hv[(size_t)c6 * 8 + lane];
        uint4 g7 = hv[(size_t)c7 * 8 + lane];
        ACCUM(g0, w0) ACCUM(g1, w1) ACCUM(g2, w2) ACCUM(g3, w3)
        ACCUM(g4, w4) ACCUM(g5, w5) ACCUM(g6, w6) ACCUM(g7, w7)
    }
    if (c & 7) {
        int e = cfull, rem = c - e;
        uint4 q = *(const uint4*)(rrow + e);
        int c0 = q.x & 0xFFFFu, c1 = q.x >> 16;
        int c2 = q.y & 0xFFFFu, c3 = q.y >> 16;
        int c4 = q.z & 0xFFFFu, c5 = q.z >> 16;
        int c6 = q.w & 0xFFFFu, c7 = q.w >> 16;
        if (rem <= 1) c1 = 0; if (rem <= 2) c2 = 0; if (rem <= 3) c3 = 0;
        if (rem <= 4) c4 = 0; if (rem <= 5) c5 = 0; if (rem <= 6) c6 = 0;
        c7 = 0;
        float w0 = EW(c0);
        float w1 = (rem > 1) ? EW(c1) : 0.f;
        float w2 = (rem > 2) ? EW(c2) : 0.f;
        float w3 = (rem > 3) ? EW(c3) : 0.f;
        float w4 = (rem > 4) ? EW(c4) : 0.f;
        float w5 = (rem > 5) ? EW(c5) : 0.f;
        float w6 = (rem > 6) ? EW(c6) : 0.f;
        float w7 = 0.f;
        uint4 g0 = hv[(size_t)c0 * 8 + lane];
        uint4 g1 = hv[(size_t)c1 * 8 + lane];
        uint4 g2 = hv[(size_t)c2 * 8 + lane];
        uint4 g3 = hv[(size_t)c3 * 8 + lane];
        uint4 g4 = hv[(size_t)c4 * 8 + lane];
        uint4 g5 = hv[(size_t)c5 * 8 + lane];
        uint4 g6 = hv[(size_t)c6 * 8 + lane];
        uint4 g7 = hv[(size_t)c7 * 8 + lane];
        ACCUM(g0, w0) ACCUM(g1, w1) ACCUM(g2, w2) ACCUM(g3, w3)
        ACCUM(g4, w4) ACCUM(g5, w5) ACCUM(g6, w6) ACCUM(g7, w7)
    }
    #undef EW
    #undef ACCUM

    const float4* bp = (const float4*)bias;
    float4 b0 = bp[lane * 2], b1 = bp[lane * 2 + 1];
    acc[0] += b0.x; acc[1] += b0.y; acc[2] += b0.z; acc[3] += b0.w;
    acc[4] += b1.x; acc[5] += b1.y; acc[6] += b1.z; acc[7] += b1.w;

    float4 o0 = make_float4(acc[0], acc[1], acc[2], acc[3]);
    float4 o1 = make_float4(acc[4], acc[5], acc[6], acc[7]);
    ((float4*)(out + (size_t)wid * 64))[lane * 2]     = o0;
    ((float4*)(out + (size_t)wid * 64))[lane * 2 + 1] = o1;
}

// ---------------- launch ----------------

extern "C" void kernel_launch(void* const* d_in, const int* in_sizes, int n_in,
                              void* d_out, int out_size, void* d_ws, size_t ws_size,
                              hipStream_t stream) {
    const float* x  = (const float*)d_in[0];
    const int*   ei = (const int*)d_in[1];     // [2, NE], row0=src, row1=dst
    const float* W1 = (const float*)d_in[2];
    const float* b1 = (const float*)d_in[3];
    const float* W2 = (const float*)d_in[4];
    const float* b2 = (const float*)d_in[5];
    const float* W3 = (const float*)d_in[6];
    const float* b3 = (const float*)d_in[7];
    float* out = (float*)d_out;

    // Workspace map (non-overlapping):
    //   cnt_g @ 0x0000000  200,000 B   (memset each run)
    //   raw   @ 0x0040000  50000*96*2 = 9,600,000 B -> 0x967C00
    //   hb    @ 0x0A00000  12,800,000 B -> 0x1635000
    //   zb    @ 0x1700000  12,800,000 B -> 0x2335000
    //   h3b   @ 0x2400000   6,400,000 B -> 0x2A1A800   (~44 MB total)
    char* w = (char*)d_ws;
    int*   cnt_g   = (int*)  (w + 0x0000000);
    unsigned short* raw = (unsigned short*)(w + 0x0040000);
    unsigned short* hb  = (unsigned short*)(w + 0x0A00000);
    unsigned short* zb  = (unsigned short*)(w + 0x1700000);
    unsigned short* h3b = (unsigned short*)(w + 0x2400000);

    const int* src = ei;
    const int* dst = ei + NE;

    hipMemsetAsync(cnt_g, 0, NN * sizeof(int), stream);
    // fused: direct CSR scatter + layer-1 GEMM (independent)
    scat_g1_kernel<<<SB + G1B, 256, 0, stream>>>(src, dst, cnt_g, raw, x, W1, hb);
    // layer 1 agg: z1 = relu(agg(h1) + b1)
    agg_bf16_kernel<true><<<(NN + 15) / 16, 256, 0, stream>>>(hb, raw, cnt_g, b1, zb);
    // layer 2
    mfma_gemm_kernel<<<G1B, 256, 0, stream>>>(zb, W2, hb);
    agg_bf16_kernel<true><<<(NN + 15) / 16, 256, 0, stream>>>(hb, raw, cnt_g, b2, zb);
    // layer 3: fp32 compute, bf16 h3; fp32 agg straight to out
    gemm3_kernel<<<G1B, 256, 0, stream>>>(zb, W3, h3b);
    agg3_kernel<<<(NN + 31) / 32, 256, 0, stream>>>(h3b, raw, cnt_g, b3, out);
}

// Round 3
// 246.661 us; speedup vs baseline: 1.0838x; 1.0838x over previous
//
#include <hip/hip_runtime.h>
#include <hip/hip_fp16.h>
#include <math.h>

#define NN 50000
#define NE 800000
#define RAWSTRIDE 96           // raw row stride (u16 col slots) per node
#define NBUCK 196              // node buckets of 256 (50000 -> 196)
#define NBBIN 196              // bin blocks: ceil(NE/ACH)
#define BCAP 4608              // per-bucket edge capacity (mean 4082, +8 sigma)
#define ACH 4096               // edges per bin block
#define G1B 782                // ceil(NN/64) gemm row-blocks

using bf8v = __attribute__((ext_vector_type(8))) short;   // 8 bf16 (4 VGPRs)
using f4v  = __attribute__((ext_vector_type(4))) float;   // 4 fp32 acc

__device__ inline unsigned short f2bf(float f) {          // RNE f32->bf16
    unsigned int u = __float_as_uint(f);
    u += 0x7FFFu + ((u >> 16) & 1u);
    return (unsigned short)(u >> 16);
}
__device__ inline float bflo(unsigned int d) { return __uint_as_float(d << 16); }
__device__ inline float bfhi(unsigned int d) { return __uint_as_float(d & 0xFFFF0000u); }

// ---------------- CSR build phase A: bin edges by dst>>8 ----------------

__device__ __forceinline__ void bin_body(const int* __restrict__ src,
                                         const int* __restrict__ dst,
                                         int* __restrict__ gcursor,
                                         unsigned int* __restrict__ bst,
                                         int bx, char* shc) {
    unsigned int* items = (unsigned int*)shc;            // ACH*4 = 16384 B
    int* cnt    = (int*)(shc + 16384);                   // 1024 B
    int* pref   = (int*)(shc + 17408);                   // 1028 B
    int* gstart = (int*)(shc + 18436);                   // 1024 B
    const int t = threadIdx.x;
    cnt[t] = 0;
    __syncthreads();
    const int base = bx * ACH;

    unsigned int my[16]; int myb[16], myr[16];
    #pragma unroll
    for (int i = 0; i < 16; ++i) {
        int e = base + i * 256 + t;
        my[i] = 0; myb[i] = -1; myr[i] = 0;
        if (e < NE) {
            int d = dst[e], s = src[e];
            my[i] = (unsigned int)s | ((unsigned int)d << 16);
            int b = d >> 8;
            myb[i] = b;
            myr[i] = atomicAdd(&cnt[b], 1);
        }
    }
    __syncthreads();
    if (t == 0) {
        int run = 0;
        for (int b = 0; b < 256; ++b) { pref[b] = run; run += cnt[b]; }
        pref[256] = run;
    }
    __syncthreads();
    if (cnt[t] > 0) gstart[t] = atomicAdd(&gcursor[t], cnt[t]);
    __syncthreads();
    #pragma unroll
    for (int i = 0; i < 16; ++i)
        if (myb[i] >= 0) items[pref[myb[i]] + myr[i]] = my[i];
    __syncthreads();
    const int total = pref[256];
    for (int i = t; i < total; i += 256) {
        int lo = 0, hi = 255;                // last b with pref[b] <= i
        while (lo < hi) { int mid = (lo + hi + 1) >> 1; if (pref[mid] <= i) lo = mid; else hi = mid - 1; }
        int idx = gstart[lo] + (i - pref[lo]);
        if (idx < BCAP) bst[(size_t)lo * BCAP + idx] = items[i];
    }
}

// ---------------- CSR build phase B: per-bucket LDS counting sort + dinv ----------------

__global__ __launch_bounds__(512) void sortb_kernel(const int* __restrict__ gcursor,
                                                    const unsigned int* __restrict__ bst,
                                                    int* __restrict__ cnt_g,
                                                    float* __restrict__ dinv,
                                                    unsigned short* __restrict__ raw) {
    __shared__ unsigned int items[BCAP];
    __shared__ int cnt[256], pref[257], cur[256];
    __shared__ unsigned short outl[BCAP];
    const int b = blockIdx.x;
    const int t = threadIdx.x;
    int n = gcursor[b];
    if (n > BCAP) n = BCAP;
    if (t < 256) { cnt[t] = 0; cur[t] = 0; }
    __syncthreads();
    for (int i = t; i < n; i += 512) {
        unsigned int u = bst[(size_t)b * BCAP + i];
        items[i] = u;
        atomicAdd(&cnt[(u >> 16) & 255], 1);
    }
    __syncthreads();
    if (t == 0) {
        int run = 0;
        for (int j = 0; j < 256; ++j) { pref[j] = run; run += cnt[j]; }
        pref[256] = run;
    }
    __syncthreads();
    for (int i = t; i < n; i += 512) {
        unsigned int u = items[i];
        int ln = (u >> 16) & 255;
        int r = atomicAdd(&cur[ln], 1);
        outl[pref[ln] + r] = (unsigned short)(u & 0xFFFFu);
    }
    __syncthreads();
    for (int i = t; i < n; i += 512) {
        int lo = 0, hi = 255;
        while (lo < hi) { int mid = (lo + hi + 1) >> 1; if (pref[mid] <= i) lo = mid; else hi = mid - 1; }
        int r = i - pref[lo];
        if (r < RAWSTRIDE) raw[(size_t)(b * 256 + lo) * RAWSTRIDE + r] = outl[i];
    }
    if (t < 256) {
        int node = b * 256 + t;
        if (node < NN) {
            int c = cnt[t];
            cnt_g[node] = c;
            dinv[node] = rsqrtf((float)(1 + c));
        }
    }
}

// ---------------- MFMA bf16 GEMM body (layers 1-2) ----------------

template <bool A_FP32>
__device__ __forceinline__ void gemm128_body(const void* __restrict__ Ain,
                                             const float* __restrict__ W,
                                             unsigned short* __restrict__ out,
                                             int bx, char* shc) {
    unsigned short* Wt = (unsigned short*)shc;            // [128][136] bf16
    unsigned short* Dt = (unsigned short*)(shc + 128 * 136 * 2);  // [64][136] bf16
    const int t = threadIdx.x;
    const int row0 = bx * 64;

    {
        int n = t & 127;
        int kbase = (t >> 7) * 4;
        for (int kk = kbase; kk < 128; kk += 8) {
            float w0 = W[(kk + 0) * 128 + n];
            float w1 = W[(kk + 1) * 128 + n];
            float w2 = W[(kk + 2) * 128 + n];
            float w3 = W[(kk + 3) * 128 + n];
            unsigned int p0 = (unsigned int)f2bf(w0) | ((unsigned int)f2bf(w1) << 16);
            unsigned int p1 = (unsigned int)f2bf(w2) | ((unsigned int)f2bf(w3) << 16);
            *(unsigned int*)&Wt[n * 136 + kk]     = p0;
            *(unsigned int*)&Wt[n * 136 + kk + 2] = p1;
        }
    }
    __syncthreads();

    const int wave = t >> 6;
    const int lane = t & 63;
    const int m16  = lane & 15;
    const int quad = lane >> 4;
    const int arow = row0 + wave * 16 + m16;
    const int arowc = (arow < NN) ? arow : 0;

    f4v acc[8];
    #pragma unroll
    for (int i = 0; i < 8; ++i) acc[i] = (f4v)(0.0f);

    #pragma unroll
    for (int k0 = 0; k0 < 128; k0 += 32) {
        bf8v afrag;
        if (A_FP32) {
            const float* A = (const float*)Ain;
            const float4* ap = (const float4*)(A + (size_t)arowc * 128 + k0 + quad * 8);
            float4 a0 = ap[0], a1 = ap[1];
            afrag[0] = (short)f2bf(a0.x); afrag[1] = (short)f2bf(a0.y);
            afrag[2] = (short)f2bf(a0.z); afrag[3] = (short)f2bf(a0.w);
            afrag[4] = (short)f2bf(a1.x); afrag[5] = (short)f2bf(a1.y);
            afrag[6] = (short)f2bf(a1.z); afrag[7] = (short)f2bf(a1.w);
        } else {
            const unsigned short* A = (const unsigned short*)Ain;
            afrag = *(const bf8v*)(A + (size_t)arowc * 128 + k0 + quad * 8);
        }
        #pragma unroll
        for (int nt = 0; nt < 8; ++nt) {
            bf8v bfrag = *(const bf8v*)&Wt[(nt * 16 + m16) * 136 + k0 + quad * 8];
            acc[nt] = __builtin_amdgcn_mfma_f32_16x16x32_bf16(afrag, bfrag, acc[nt], 0, 0, 0);
        }
    }

    #pragma unroll
    for (int nt = 0; nt < 8; ++nt) {
        #pragma unroll
        for (int r = 0; r < 4; ++r) {
            Dt[(wave * 16 + quad * 4 + r) * 136 + nt * 16 + m16] = f2bf(acc[nt][r]);
        }
    }
    __syncthreads();

    {
        int r = t >> 2;
        int c = t & 3;
        int gr = row0 + r;
        if (gr < NN) {
            const uint4* s = (const uint4*)&Dt[r * 136] + c * 4;
            uint4* d = (uint4*)(out + (size_t)gr * 128) + c * 4;
            d[0] = s[0]; d[1] = s[1]; d[2] = s[2]; d[3] = s[3];
        }
    }
}

// fused: bin (196 blocks) + gemm1 (782 blocks) — independent work, one launch
__global__ __launch_bounds__(256) void bin_g1_kernel(const int* __restrict__ src,
                                                     const int* __restrict__ dst,
                                                     int* __restrict__ gcursor,
                                                     unsigned int* __restrict__ bst,
                                                     const float* __restrict__ x,
                                                     const float* __restrict__ W1,
                                                     unsigned short* __restrict__ hb) {
    __shared__ __align__(16) char sh[52224];   // max(gemm 52224, bin 19460)
    if (blockIdx.x < NBBIN) {
        bin_body(src, dst, gcursor, bst, blockIdx.x, sh);
    } else {
        gemm128_body<true>(x, W1, hb, blockIdx.x - NBBIN, sh);
    }
}

// standalone gemm (layer 2)
__global__ __launch_bounds__(256) void mfma_gemm_kernel(const unsigned short* __restrict__ Ain,
                                                        const float* __restrict__ W,
                                                        unsigned short* __restrict__ out) {
    __shared__ __align__(16) char sh[52224];
    gemm128_body<false>(Ain, W, out, blockIdx.x, sh);
}

// ---------------- bf16 pull aggregation (layers 1-2) ----------------
// 16 lanes/group, 16 groups/block, 8-edge chunks with next-chunk index prefetch.
// weight = dinv[wid]*dinv[col]; dinv is a 200KB L2-resident broadcast table.

template <bool RELU>
__global__ __launch_bounds__(256) void agg_bf16_kernel(const unsigned short* __restrict__ hin,
                                                       const unsigned short* __restrict__ raw,
                                                       const int* __restrict__ cnt_g,
                                                       const float* __restrict__ dinv,
                                                       const float* __restrict__ bias,
                                                       unsigned short* __restrict__ outb) {
    const int t = threadIdx.x;
    const int group = t >> 4;
    const int lane  = t & 15;
    const int wid = blockIdx.x * 16 + group;
    if (wid >= NN) return;

    int c = cnt_g[wid];
    if (c > RAWSTRIDE) c = RAWSTRIDE;
    const float diw = dinv[wid];
    const unsigned short* rrow = raw + (size_t)wid * RAWSTRIDE;
    const uint4* hv = (const uint4*)hin;

    float acc[8];
    {   // self loop, fp32 weight
        uint4 g = hv[(size_t)wid * 16 + lane];
        float ws = diw * diw;
        acc[0] = ws * bflo(g.x); acc[1] = ws * bfhi(g.x);
        acc[2] = ws * bflo(g.y); acc[3] = ws * bfhi(g.y);
        acc[4] = ws * bflo(g.z); acc[5] = ws * bfhi(g.z);
        acc[6] = ws * bflo(g.w); acc[7] = ws * bfhi(g.w);
    }

    #define ACCUM(G, W_) \
        acc[0] += W_ * bflo(G.x); acc[1] += W_ * bfhi(G.x); \
        acc[2] += W_ * bflo(G.y); acc[3] += W_ * bfhi(G.y); \
        acc[4] += W_ * bflo(G.z); acc[5] += W_ * bfhi(G.z); \
        acc[6] += W_ * bflo(G.w); acc[7] += W_ * bfhi(G.w);

    const int cfull = c & ~7;
    uint4 q;
    if (cfull > 0) q = *(const uint4*)(rrow);
    for (int e = 0; e < cfull; e += 8) {
        uint4 qc = q;
        if (e + 8 < cfull) q = *(const uint4*)(rrow + e + 8);   // prefetch next indices
        int c0 = qc.x & 0xFFFFu, c1 = qc.x >> 16;
        int c2 = qc.y & 0xFFFFu, c3 = qc.y >> 16;
        int c4 = qc.z & 0xFFFFu, c5 = qc.z >> 16;
        int c6 = qc.w & 0xFFFFu, c7 = qc.w >> 16;
        uint4 g0 = hv[(size_t)c0 * 16 + lane];
        uint4 g1 = hv[(size_t)c1 * 16 + lane];
        uint4 g2 = hv[(size_t)c2 * 16 + lane];
        uint4 g3 = hv[(size_t)c3 * 16 + lane];
        uint4 g4 = hv[(size_t)c4 * 16 + lane];
        uint4 g5 = hv[(size_t)c5 * 16 + lane];
        uint4 g6 = hv[(size_t)c6 * 16 + lane];
        uint4 g7 = hv[(size_t)c7 * 16 + lane];
        float w0 = diw * dinv[c0], w1 = diw * dinv[c1];
        float w2 = diw * dinv[c2], w3 = diw * dinv[c3];
        float w4 = diw * dinv[c4], w5 = diw * dinv[c5];
        float w6 = diw * dinv[c6], w7 = diw * dinv[c7];
        ACCUM(g0, w0) ACCUM(g1, w1) ACCUM(g2, w2) ACCUM(g3, w3)
        ACCUM(g4, w4) ACCUM(g5, w5) ACCUM(g6, w6) ACCUM(g7, w7)
    }
    if (c & 7) {                       // predicated tail chunk
        int e = cfull, rem = c - e;    // 1..7
        uint4 qc = *(const uint4*)(rrow + e);
        int c0 = qc.x & 0xFFFFu, c1 = qc.x >> 16;
        int c2 = qc.y & 0xFFFFu, c3 = qc.y >> 16;
        int c4 = qc.z & 0xFFFFu, c5 = qc.z >> 16;
        int c6 = qc.w & 0xFFFFu, c7 = qc.w >> 16;
        if (rem <= 1) c1 = 0; if (rem <= 2) c2 = 0; if (rem <= 3) c3 = 0;
        if (rem <= 4) c4 = 0; if (rem <= 5) c5 = 0; if (rem <= 6) c6 = 0;
        c7 = 0;
        float w0 = diw * dinv[c0];
        float w1 = (rem > 1) ? diw * dinv[c1] : 0.f;
        float w2 = (rem > 2) ? diw * dinv[c2] : 0.f;
        float w3 = (rem > 3) ? diw * dinv[c3] : 0.f;
        float w4 = (rem > 4) ? diw * dinv[c4] : 0.f;
        float w5 = (rem > 5) ? diw * dinv[c5] : 0.f;
        float w6 = (rem > 6) ? diw * dinv[c6] : 0.f;
        float w7 = 0.f;
        uint4 g0 = hv[(size_t)c0 * 16 + lane];
        uint4 g1 = hv[(size_t)c1 * 16 + lane];
        uint4 g2 = hv[(size_t)c2 * 16 + lane];
        uint4 g3 = hv[(size_t)c3 * 16 + lane];
        uint4 g4 = hv[(size_t)c4 * 16 + lane];
        uint4 g5 = hv[(size_t)c5 * 16 + lane];
        uint4 g6 = hv[(size_t)c6 * 16 + lane];
        uint4 g7 = hv[(size_t)c7 * 16 + lane];
        ACCUM(g0, w0) ACCUM(g1, w1) ACCUM(g2, w2) ACCUM(g3, w3)
        ACCUM(g4, w4) ACCUM(g5, w5) ACCUM(g6, w6) ACCUM(g7, w7)
    }
    #undef ACCUM

    const float4* bp = (const float4*)bias;
    float4 b0 = bp[lane * 2], b1 = bp[lane * 2 + 1];
    acc[0] += b0.x; acc[1] += b0.y; acc[2] += b0.z; acc[3] += b0.w;
    acc[4] += b1.x; acc[5] += b1.y; acc[6] += b1.z; acc[7] += b1.w;
    if (RELU) {
        #pragma unroll
        for (int j = 0; j < 8; ++j) acc[j] = fmaxf(acc[j], 0.f);
    }
    uint4 o;
    o.x = (unsigned int)f2bf(acc[0]) | ((unsigned int)f2bf(acc[1]) << 16);
    o.y = (unsigned int)f2bf(acc[2]) | ((unsigned int)f2bf(acc[3]) << 16);
    o.z = (unsigned int)f2bf(acc[4]) | ((unsigned int)f2bf(acc[5]) << 16);
    o.w = (unsigned int)f2bf(acc[6]) | ((unsigned int)f2bf(acc[7]) << 16);
    ((uint4*)(outb + (size_t)wid * 128))[lane] = o;
}

// ---------------- layer-3 GEMM (fp32 compute, bf16 in, bf16 out) ----------------

__global__ __launch_bounds__(256) void gemm3_kernel(const unsigned short* __restrict__ Ab,
                                                    const float* __restrict__ W,
                                                    unsigned short* __restrict__ outh) {
    constexpr int CG = 16;
    constexpr int RPT = 4;
    constexpr int ROWS = 64;
    constexpr int LD = 132;
    __shared__ float lds[ROWS * LD];
    const int t = threadIdx.x;
    const int row0 = blockIdx.x * ROWS;

    #pragma unroll
    for (int j = 0; j < ROWS / 8; ++j) {
        int idx4 = j * 256 + t;
        int r = idx4 >> 5, c4 = idx4 & 31;
        int gr = row0 + r;
        uint2 u = make_uint2(0u, 0u);
        if (gr < NN) u = ((const uint2*)(Ab + (size_t)gr * 128))[c4];
        float4 v;
        v.x = bflo(u.x); v.y = bfhi(u.x); v.z = bflo(u.y); v.w = bfhi(u.y);
        ((float4*)(lds + r * LD))[c4] = v;
    }
    __syncthreads();

    const int cg = t % CG;
    const int rt = t / CG;
    const float4* Wv = (const float4*)W;
    float4 acc[RPT];
    #pragma unroll
    for (int i = 0; i < RPT; ++i) acc[i] = make_float4(0.f, 0.f, 0.f, 0.f);

    for (int k0 = 0; k0 < 128; k0 += 4) {
        float4 w0 = Wv[(k0 + 0) * CG + cg];
        float4 w1 = Wv[(k0 + 1) * CG + cg];
        float4 w2 = Wv[(k0 + 2) * CG + cg];
        float4 w3 = Wv[(k0 + 3) * CG + cg];
        #pragma unroll
        for (int i = 0; i < RPT; ++i) {
            const float* lr = lds + (rt * RPT + i) * LD;
            float4 a = ((const float4*)lr)[k0 >> 2];
            acc[i].x += a.x * w0.x + a.y * w1.x + a.z * w2.x + a.w * w3.x;
            acc[i].y += a.x * w0.y + a.y * w1.y + a.z * w2.y + a.w * w3.y;
            acc[i].z += a.x * w0.z + a.y * w1.z + a.z * w2.z + a.w * w3.z;
            acc[i].w += a.x * w0.w + a.y * w1.w + a.z * w2.w + a.w * w3.w;
        }
    }

    #pragma unroll
    for (int i = 0; i < RPT; ++i) {
        int gr = row0 + rt * RPT + i;
        if (gr < NN) {
            uint2 o;
            o.x = (unsigned int)f2bf(acc[i].x) | ((unsigned int)f2bf(acc[i].y) << 16);
            o.y = (unsigned int)f2bf(acc[i].z) | ((unsigned int)f2bf(acc[i].w) << 16);
            ((uint2*)(outh + (size_t)gr * 64))[cg] = o;
        }
    }
}

// ---------------- layer-3 aggregation: bf16 gather (128B rows) -> fp32 out ----------------

__global__ __launch_bounds__(256) void agg3_kernel(const unsigned short* __restrict__ hin,
                                                   const unsigned short* __restrict__ raw,
                                                   const int* __restrict__ cnt_g,
                                                   const float* __restrict__ dinv,
                                                   const float* __restrict__ bias,
                                                   float* __restrict__ out) {
    const int t = threadIdx.x;
    const int group = t >> 3;
    const int lane  = t & 7;
    const int wid = blockIdx.x * 32 + group;
    if (wid >= NN) return;

    int c = cnt_g[wid];
    if (c > RAWSTRIDE) c = RAWSTRIDE;
    const float diw = dinv[wid];
    const unsigned short* rrow = raw + (size_t)wid * RAWSTRIDE;
    const uint4* hv = (const uint4*)hin;      // 8 uint4 per 64-feat bf16 row

    float acc[8];
    {   // self loop
        uint4 g = hv[(size_t)wid * 8 + lane];
        float ws = diw * diw;
        acc[0] = ws * bflo(g.x); acc[1] = ws * bfhi(g.x);
        acc[2] = ws * bflo(g.y); acc[3] = ws * bfhi(g.y);
        acc[4] = ws * bflo(g.z); acc[5] = ws * bfhi(g.z);
        acc[6] = ws * bflo(g.w); acc[7] = ws * bfhi(g.w);
    }

    #define ACCUM(G, W_) \
        acc[0] += W_ * bflo(G.x); acc[1] += W_ * bfhi(G.x); \
        acc[2] += W_ * bflo(G.y); acc[3] += W_ * bfhi(G.y); \
        acc[4] += W_ * bflo(G.z); acc[5] += W_ * bfhi(G.z); \
        acc[6] += W_ * bflo(G.w); acc[7] += W_ * bfhi(G.w);

    const int cfull = c & ~7;
    uint4 q;
    if (cfull > 0) q = *(const uint4*)(rrow);
    for (int e = 0; e < cfull; e += 8) {
        uint4 qc = q;
        if (e + 8 < cfull) q = *(const uint4*)(rrow + e + 8);   // prefetch next indices
        int c0 = qc.x & 0xFFFFu, c1 = qc.x >> 16;
        int c2 = qc.y & 0xFFFFu, c3 = qc.y >> 16;
        int c4 = qc.z & 0xFFFFu, c5 = qc.z >> 16;
        int c6 = qc.w & 0xFFFFu, c7 = qc.w >> 16;
        uint4 g0 = hv[(size_t)c0 * 8 + lane];
        uint4 g1 = hv[(size_t)c1 * 8 + lane];
        uint4 g2 = hv[(size_t)c2 * 8 + lane];
        uint4 g3 = hv[(size_t)c3 * 8 + lane];
        uint4 g4 = hv[(size_t)c4 * 8 + lane];
        uint4 g5 = hv[(size_t)c5 * 8 + lane];
        uint4 g6 = hv[(size_t)c6 * 8 + lane];
        uint4 g7 = hv[(size_t)c7 * 8 + lane];
        float w0 = diw * dinv[c0], w1 = diw * dinv[c1];
        float w2 = diw * dinv[c2], w3 = diw * dinv[c3];
        float w4 = diw * dinv[c4], w5 = diw * dinv[c5];
        float w6 = diw * dinv[c6], w7 = diw * dinv[c7];
        ACCUM(g0, w0) ACCUM(g1, w1) ACCUM(g2, w2) ACCUM(g3, w3)
        ACCUM(g4, w4) ACCUM(g5, w5) ACCUM(g6, w6) ACCUM(g7, w7)
    }
    if (c & 7) {
        int e = cfull, rem = c - e;
        uint4 qc = *(const uint4*)(rrow + e);
        int c0 = qc.x & 0xFFFFu, c1 = qc.x >> 16;
        int c2 = qc.y & 0xFFFFu, c3 = qc.y >> 16;
        int c4 = qc.z & 0xFFFFu, c5 = qc.z >> 16;
        int c6 = qc.w & 0xFFFFu, c7 = qc.w >> 16;
        if (rem <= 1) c1 = 0; if (rem <= 2) c2 = 0; if (rem <= 3) c3 = 0;
        if (rem <= 4) c4 = 0; if (rem <= 5) c5 = 0; if (rem <= 6) c6 = 0;
        c7 = 0;
        float w0 = diw * dinv[c0];
        float w1 = (rem > 1) ? diw * dinv[c1] : 0.f;
        float w2 = (rem > 2) ? diw * dinv[c2] : 0.f;
        float w3 = (rem > 3) ? diw * dinv[c3] : 0.f;
        float w4 = (rem > 4) ? diw * dinv[c4] : 0.f;
        float w5 = (rem > 5) ? diw * dinv[c5] : 0.f;
        float w6 = (rem > 6) ? diw * dinv[c6] : 0.f;
        float w7 = 0.f;
        uint4 g0 = hv[(size_t)c0 * 8 + lane];
        uint4 g1 = hv[(size_t)c1 * 8 + lane];
        uint4 g2 = hv[(size_t)c2 * 8 + lane];
        uint4 g3 = hv[(size_t)c3 * 8 + lane];
        uint4 g4 = hv[(size_t)c4 * 8 + lane];
        uint4 g5 = hv[(size_t)c5 * 8 + lane];
        uint4 g6 = hv[(size_t)c6 * 8 + lane];
        uint4 g7 = hv[(size_t)c7 * 8 + lane];
        ACCUM(g0, w0) ACCUM(g1, w1) ACCUM(g2, w2) ACCUM(g3, w3)
        ACCUM(g4, w4) ACCUM(g5, w5) ACCUM(g6, w6) ACCUM(g7, w7)
    }
    #undef ACCUM

    const float4* bp = (const float4*)bias;
    float4 b0 = bp[lane * 2], b1 = bp[lane * 2 + 1];
    acc[0] += b0.x; acc[1] += b0.y; acc[2] += b0.z; acc[3] += b0.w;
    acc[4] += b1.x; acc[5] += b1.y; acc[6] += b1.z; acc[7] += b1.w;

    float4 o0 = make_float4(acc[0], acc[1], acc[2], acc[3]);
    float4 o1 = make_float4(acc[4], acc[5], acc[6], acc[7]);
    ((float4*)(out + (size_t)wid * 64))[lane * 2]     = o0;
    ((float4*)(out + (size_t)wid * 64))[lane * 2 + 1] = o1;
}

// ---------------- launch ----------------

extern "C" void kernel_launch(void* const* d_in, const int* in_sizes, int n_in,
                              void* d_out, int out_size, void* d_ws, size_t ws_size,
                              hipStream_t stream) {
    const float* x  = (const float*)d_in[0];
    const int*   ei = (const int*)d_in[1];     // [2, NE], row0=src, row1=dst
    const float* W1 = (const float*)d_in[2];
    const float* b1 = (const float*)d_in[3];
    const float* W2 = (const float*)d_in[4];
    const float* b2 = (const float*)d_in[5];
    const float* W3 = (const float*)d_in[6];
    const float* b3 = (const float*)d_in[7];
    float* out = (float*)d_out;

    // Workspace map:
    //   cnt_g   @ 0x0000000  200,000 B
    //   gcursor @ 0x0040000  784 B       (memset only this)
    //   dinv    @ 0x0048000  200,000 B
    //   bst     @ 0x0080000  3,612,672 B -> 0x3B2200
    //   raw     @ 0x0400000  9,600,000 B -> 0xD27F80
    //   hb      @ 0x0E00000  12,800,000 B
    //   zb      @ 0x1B00000  12,800,000 B
    //   h3b     @ 0x2800000   6,400,000 B   (~48 MB total)
    char* w = (char*)d_ws;
    int*   cnt_g   = (int*)  (w + 0x0000000);
    int*   gcursor = (int*)  (w + 0x0040000);
    float* dinv    = (float*)(w + 0x0048000);
    unsigned int*   bst = (unsigned int*)  (w + 0x0080000);
    unsigned short* raw = (unsigned short*)(w + 0x0400000);
    unsigned short* hb  = (unsigned short*)(w + 0x0E00000);
    unsigned short* zb  = (unsigned short*)(w + 0x1B00000);
    unsigned short* h3b = (unsigned short*)(w + 0x2800000);

    const int* src = ei;
    const int* dst = ei + NE;

    hipMemsetAsync(gcursor, 0, NBUCK * sizeof(int), stream);
    // fused: CSR binning + layer-1 GEMM (independent)
    bin_g1_kernel<<<NBBIN + G1B, 256, 0, stream>>>(src, dst, gcursor, bst, x, W1, hb);
    sortb_kernel<<<NBUCK, 512, 0, stream>>>(gcursor, bst, cnt_g, dinv, raw);
    // layer 1 agg: z1 = relu(agg(h1) + b1)
    agg_bf16_kernel<true><<<(NN + 15) / 16, 256, 0, stream>>>(hb, raw, cnt_g, dinv, b1, zb);
    // layer 2
    mfma_gemm_kernel<<<G1B, 256, 0, stream>>>(zb, W2, hb);
    agg_bf16_kernel<true><<<(NN + 15) / 16, 256, 0, stream>>>(hb, raw, cnt_g, dinv, b2, zb);
    // layer 3: fp32 compute, bf16 h3; fp32 agg straight to out
    gemm3_kernel<<<G1B, 256, 0, stream>>>(zb, W3, h3b);
    agg3_kernel<<<(NN + 31) / 32, 256, 0, stream>>>(h3b, raw, cnt_g, dinv, b3, out);
}

// Round 4
// 239.391 us; speedup vs baseline: 1.1167x; 1.0304x over previous
//
#include <hip/hip_runtime.h>
#include <hip/hip_fp16.h>
#include <math.h>

#define NN 50000
#define NE 800000
#define RAWSTRIDE 96           // raw row stride (u16 col slots) per node
#define NBUCK 196              // node buckets of 256 (50000 -> 196)
#define NBBIN 196              // bin blocks: ceil(NE/ACH)
#define BCAP 4608              // per-bucket edge capacity (mean 4082, +8 sigma)
#define ACH 4096               // edges per bin block
#define G1B 782                // ceil(NN/64) row-blocks

using bf8v = __attribute__((ext_vector_type(8))) short;   // 8 bf16 (4 VGPRs)
using f4v  = __attribute__((ext_vector_type(4))) float;   // 4 fp32 acc

__device__ inline unsigned short f2bf(float f) {          // RNE f32->bf16
    unsigned int u = __float_as_uint(f);
    u += 0x7FFFu + ((u >> 16) & 1u);
    return (unsigned short)(u >> 16);
}
__device__ inline float bflo(unsigned int d) { return __uint_as_float(d << 16); }
__device__ inline float bfhi(unsigned int d) { return __uint_as_float(d & 0xFFFF0000u); }

// ---------------- CSR build phase A: bin edges by dst>>8 ----------------

__device__ __forceinline__ void bin_body(const int* __restrict__ src,
                                         const int* __restrict__ dst,
                                         int* __restrict__ gcursor,
                                         unsigned int* __restrict__ bst,
                                         int bx, char* shc) {
    unsigned int* items = (unsigned int*)shc;            // ACH*4 = 16384 B
    int* cnt    = (int*)(shc + 16384);                   // 1024 B
    int* pref   = (int*)(shc + 17408);                   // 1028 B
    int* gstart = (int*)(shc + 18436);                   // 1024 B
    const int t = threadIdx.x;
    cnt[t] = 0;
    __syncthreads();
    const int base = bx * ACH;

    unsigned int my[16]; int myb[16], myr[16];
    #pragma unroll
    for (int i = 0; i < 16; ++i) {
        int e = base + i * 256 + t;
        my[i] = 0; myb[i] = -1; myr[i] = 0;
        if (e < NE) {
            int d = dst[e], s = src[e];
            my[i] = (unsigned int)s | ((unsigned int)d << 16);
            int b = d >> 8;
            myb[i] = b;
            myr[i] = atomicAdd(&cnt[b], 1);
        }
    }
    __syncthreads();
    if (t == 0) {
        int run = 0;
        for (int b = 0; b < 256; ++b) { pref[b] = run; run += cnt[b]; }
        pref[256] = run;
    }
    __syncthreads();
    if (cnt[t] > 0) gstart[t] = atomicAdd(&gcursor[t], cnt[t]);
    __syncthreads();
    #pragma unroll
    for (int i = 0; i < 16; ++i)
        if (myb[i] >= 0) items[pref[myb[i]] + myr[i]] = my[i];
    __syncthreads();
    const int total = pref[256];
    for (int i = t; i < total; i += 256) {
        int lo = 0, hi = 255;                // last b with pref[b] <= i
        while (lo < hi) { int mid = (lo + hi + 1) >> 1; if (pref[mid] <= i) lo = mid; else hi = mid - 1; }
        int idx = gstart[lo] + (i - pref[lo]);
        if (idx < BCAP) bst[(size_t)lo * BCAP + idx] = items[i];
    }
}

// ---------------- CSR build phase B: per-bucket LDS counting sort + dinv ----------------

__global__ __launch_bounds__(512) void sortb_kernel(const int* __restrict__ gcursor,
                                                    const unsigned int* __restrict__ bst,
                                                    int* __restrict__ cnt_g,
                                                    float* __restrict__ dinv,
                                                    unsigned short* __restrict__ raw) {
    __shared__ unsigned int items[BCAP];
    __shared__ int cnt[256], pref[257], cur[256];
    __shared__ unsigned short outl[BCAP];
    const int b = blockIdx.x;
    const int t = threadIdx.x;
    int n = gcursor[b];
    if (n > BCAP) n = BCAP;
    if (t < 256) { cnt[t] = 0; cur[t] = 0; }
    __syncthreads();
    for (int i = t; i < n; i += 512) {
        unsigned int u = bst[(size_t)b * BCAP + i];
        items[i] = u;
        atomicAdd(&cnt[(u >> 16) & 255], 1);
    }
    __syncthreads();
    if (t == 0) {
        int run = 0;
        for (int j = 0; j < 256; ++j) { pref[j] = run; run += cnt[j]; }
        pref[256] = run;
    }
    __syncthreads();
    for (int i = t; i < n; i += 512) {
        unsigned int u = items[i];
        int ln = (u >> 16) & 255;
        int r = atomicAdd(&cur[ln], 1);
        outl[pref[ln] + r] = (unsigned short)(u & 0xFFFFu);
    }
    __syncthreads();
    for (int i = t; i < n; i += 512) {
        int lo = 0, hi = 255;
        while (lo < hi) { int mid = (lo + hi + 1) >> 1; if (pref[mid] <= i) lo = mid; else hi = mid - 1; }
        int r = i - pref[lo];
        if (r < RAWSTRIDE) raw[(size_t)(b * 256 + lo) * RAWSTRIDE + r] = outl[i];
    }
    if (t < 256) {
        int node = b * 256 + t;
        if (node < NN) {
            int c = cnt[t];
            cnt_g[node] = c;
            dinv[node] = rsqrtf((float)(1 + c));
        }
    }
}

// ---------------- MFMA bf16 GEMM body (layer 1): out_bf16[Nx128] = A[Nx128] @ W[128x128] ----

__device__ __forceinline__ void gemm128_body_f32(const float* __restrict__ A,
                                                 const float* __restrict__ W,
                                                 unsigned short* __restrict__ out,
                                                 int bx, char* shc) {
    unsigned short* Wt = (unsigned short*)shc;            // [128][136] bf16
    unsigned short* Dt = (unsigned short*)(shc + 128 * 136 * 2);  // [64][136] bf16
    const int t = threadIdx.x;
    const int row0 = bx * 64;

    {
        int n = t & 127;
        int kbase = (t >> 7) * 4;
        for (int kk = kbase; kk < 128; kk += 8) {
            float w0 = W[(kk + 0) * 128 + n];
            float w1 = W[(kk + 1) * 128 + n];
            float w2 = W[(kk + 2) * 128 + n];
            float w3 = W[(kk + 3) * 128 + n];
            unsigned int p0 = (unsigned int)f2bf(w0) | ((unsigned int)f2bf(w1) << 16);
            unsigned int p1 = (unsigned int)f2bf(w2) | ((unsigned int)f2bf(w3) << 16);
            *(unsigned int*)&Wt[n * 136 + kk]     = p0;
            *(unsigned int*)&Wt[n * 136 + kk + 2] = p1;
        }
    }
    __syncthreads();

    const int wave = t >> 6;
    const int lane = t & 63;
    const int m16  = lane & 15;
    const int quad = lane >> 4;
    const int arow = row0 + wave * 16 + m16;
    const int arowc = (arow < NN) ? arow : 0;

    f4v acc[8];
    #pragma unroll
    for (int i = 0; i < 8; ++i) acc[i] = (f4v)(0.0f);

    #pragma unroll
    for (int k0 = 0; k0 < 128; k0 += 32) {
        bf8v afrag;
        const float4* ap = (const float4*)(A + (size_t)arowc * 128 + k0 + quad * 8);
        float4 a0 = ap[0], a1 = ap[1];
        afrag[0] = (short)f2bf(a0.x); afrag[1] = (short)f2bf(a0.y);
        afrag[2] = (short)f2bf(a0.z); afrag[3] = (short)f2bf(a0.w);
        afrag[4] = (short)f2bf(a1.x); afrag[5] = (short)f2bf(a1.y);
        afrag[6] = (short)f2bf(a1.z); afrag[7] = (short)f2bf(a1.w);
        #pragma unroll
        for (int nt = 0; nt < 8; ++nt) {
            bf8v bfrag = *(const bf8v*)&Wt[(nt * 16 + m16) * 136 + k0 + quad * 8];
            acc[nt] = __builtin_amdgcn_mfma_f32_16x16x32_bf16(afrag, bfrag, acc[nt], 0, 0, 0);
        }
    }

    #pragma unroll
    for (int nt = 0; nt < 8; ++nt) {
        #pragma unroll
        for (int r = 0; r < 4; ++r) {
            Dt[(wave * 16 + quad * 4 + r) * 136 + nt * 16 + m16] = f2bf(acc[nt][r]);
        }
    }
    __syncthreads();

    {
        int r = t >> 2;
        int c = t & 3;
        int gr = row0 + r;
        if (gr < NN) {
            const uint4* s = (const uint4*)&Dt[r * 136] + c * 4;
            uint4* d = (uint4*)(out + (size_t)gr * 128) + c * 4;
            d[0] = s[0]; d[1] = s[1]; d[2] = s[2]; d[3] = s[3];
        }
    }
}

// fused: bin (196 blocks) + gemm1 (782 blocks) — independent work, one launch
__global__ __launch_bounds__(256) void bin_g1_kernel(const int* __restrict__ src,
                                                     const int* __restrict__ dst,
                                                     int* __restrict__ gcursor,
                                                     unsigned int* __restrict__ bst,
                                                     const float* __restrict__ x,
                                                     const float* __restrict__ W1,
                                                     unsigned short* __restrict__ hb) {
    __shared__ __align__(16) char sh[52224];   // max(gemm 52224, bin 19460)
    if (blockIdx.x < NBBIN) {
        bin_body(src, dst, gcursor, bst, blockIdx.x, sh);
    } else {
        gemm128_body_f32(x, W1, hb, blockIdx.x - NBBIN, sh);
    }
}

// ---------------- agg loop macro (128-feat bf16 rows, 16 lanes/group) ----------------
// Produces acc[8] (fp32) = sum over self-loop + in-edges of w * h[col][lane*8 .. +7].

#define AGG128_BODY(HV, RROW, C, DIW, LANE, ACCV)                                   \
    {                                                                               \
        uint4 g = HV[(size_t)wid * 16 + (LANE)];                                    \
        float ws = (DIW) * (DIW);                                                   \
        ACCV[0] = ws * bflo(g.x); ACCV[1] = ws * bfhi(g.x);                         \
        ACCV[2] = ws * bflo(g.y); ACCV[3] = ws * bfhi(g.y);                         \
        ACCV[4] = ws * bflo(g.z); ACCV[5] = ws * bfhi(g.z);                         \
        ACCV[6] = ws * bflo(g.w); ACCV[7] = ws * bfhi(g.w);                         \
    }                                                                               \
    const int cfull = (C) & ~7;                                                     \
    uint4 q;                                                                        \
    if (cfull > 0) q = *(const uint4*)(RROW);                                       \
    for (int e = 0; e < cfull; e += 8) {                                            \
        uint4 qc = q;                                                               \
        if (e + 8 < cfull) q = *(const uint4*)((RROW) + e + 8);                     \
        int c0 = qc.x & 0xFFFFu, c1 = qc.x >> 16;                                   \
        int c2 = qc.y & 0xFFFFu, c3 = qc.y >> 16;                                   \
        int c4 = qc.z & 0xFFFFu, c5 = qc.z >> 16;                                   \
        int c6 = qc.w & 0xFFFFu, c7 = qc.w >> 16;                                   \
        uint4 g0 = HV[(size_t)c0 * 16 + (LANE)];                                    \
        uint4 g1 = HV[(size_t)c1 * 16 + (LANE)];                                    \
        uint4 g2 = HV[(size_t)c2 * 16 + (LANE)];                                    \
        uint4 g3 = HV[(size_t)c3 * 16 + (LANE)];                                    \
        uint4 g4 = HV[(size_t)c4 * 16 + (LANE)];                                    \
        uint4 g5 = HV[(size_t)c5 * 16 + (LANE)];                                    \
        uint4 g6 = HV[(size_t)c6 * 16 + (LANE)];                                    \
        uint4 g7 = HV[(size_t)c7 * 16 + (LANE)];                                    \
        float w0 = (DIW) * dinv[c0], w1 = (DIW) * dinv[c1];                         \
        float w2 = (DIW) * dinv[c2], w3 = (DIW) * dinv[c3];                         \
        float w4 = (DIW) * dinv[c4], w5 = (DIW) * dinv[c5];                         \
        float w6 = (DIW) * dinv[c6], w7 = (DIW) * dinv[c7];                         \
        ACC8(g0, w0) ACC8(g1, w1) ACC8(g2, w2) ACC8(g3, w3)                         \
        ACC8(g4, w4) ACC8(g5, w5) ACC8(g6, w6) ACC8(g7, w7)                         \
    }                                                                               \
    if ((C) & 7) {                                                                  \
        int e = cfull, rem = (C) - e;                                               \
        uint4 qc = *(const uint4*)((RROW) + e);                                     \
        int c0 = qc.x & 0xFFFFu, c1 = qc.x >> 16;                                   \
        int c2 = qc.y & 0xFFFFu, c3 = qc.y >> 16;                                   \
        int c4 = qc.z & 0xFFFFu, c5 = qc.z >> 16;                                   \
        int c6 = qc.w & 0xFFFFu, c7 = qc.w >> 16;                                   \
        if (rem <= 1) c1 = 0; if (rem <= 2) c2 = 0; if (rem <= 3) c3 = 0;           \
        if (rem <= 4) c4 = 0; if (rem <= 5) c5 = 0; if (rem <= 6) c6 = 0;           \
        c7 = 0;                                                                     \
        float w0 = (DIW) * dinv[c0];                                                \
        float w1 = (rem > 1) ? (DIW) * dinv[c1] : 0.f;                              \
        float w2 = (rem > 2) ? (DIW) * dinv[c2] : 0.f;                              \
        float w3 = (rem > 3) ? (DIW) * dinv[c3] : 0.f;                              \
        float w4 = (rem > 4) ? (DIW) * dinv[c4] : 0.f;                              \
        float w5 = (rem > 5) ? (DIW) * dinv[c5] : 0.f;                              \
        float w6 = (rem > 6) ? (DIW) * dinv[c6] : 0.f;                              \
        float w7 = 0.f;                                                             \
        uint4 g0 = HV[(size_t)c0 * 16 + (LANE)];                                    \
        uint4 g1 = HV[(size_t)c1 * 16 + (LANE)];                                    \
        uint4 g2 = HV[(size_t)c2 * 16 + (LANE)];                                    \
        uint4 g3 = HV[(size_t)c3 * 16 + (LANE)];                                    \
        uint4 g4 = HV[(size_t)c4 * 16 + (LANE)];                                    \
        uint4 g5 = HV[(size_t)c5 * 16 + (LANE)];                                    \
        uint4 g6 = HV[(size_t)c6 * 16 + (LANE)];                                    \
        uint4 g7 = HV[(size_t)c7 * 16 + (LANE)];                                    \
        ACC8(g0, w0) ACC8(g1, w1) ACC8(g2, w2) ACC8(g3, w3)                         \
        ACC8(g4, w4) ACC8(g5, w5) ACC8(g6, w6) ACC8(g7, w7)                         \
    }

#define ACC8(G, W_) \
    acc[0] += W_ * bflo(G.x); acc[1] += W_ * bfhi(G.x); \
    acc[2] += W_ * bflo(G.y); acc[3] += W_ * bfhi(G.y); \
    acc[4] += W_ * bflo(G.z); acc[5] += W_ * bfhi(G.z); \
    acc[6] += W_ * bflo(G.w); acc[7] += W_ * bfhi(G.w);

// ---------------- fused layer-1 agg + layer-2 GEMM ----------------
// Block owns 64 nodes: agg z1 = relu(Â·hb + b1) into LDS bf16 tile, then MFMA z1@W2 -> h2b.

__global__ __launch_bounds__(256) void aggW2_kernel(const unsigned short* __restrict__ hin,
                                                    const unsigned short* __restrict__ raw,
                                                    const int* __restrict__ cnt_g,
                                                    const float* __restrict__ dinv,
                                                    const float* __restrict__ bias,
                                                    const float* __restrict__ W,
                                                    unsigned short* __restrict__ out) {
    __shared__ unsigned short Wt[128 * 136];   // W2 bf16 [n][k]
    __shared__ unsigned short Zt[64 * 136];    // z1 tile bf16 [m][k]; later aliased as Dt
    const int t = threadIdx.x;
    const int row0 = blockIdx.x * 64;

    {   // stage W2
        int n = t & 127;
        int kbase = (t >> 7) * 4;
        for (int kk = kbase; kk < 128; kk += 8) {
            float w0 = W[(kk + 0) * 128 + n];
            float w1 = W[(kk + 1) * 128 + n];
            float w2 = W[(kk + 2) * 128 + n];
            float w3 = W[(kk + 3) * 128 + n];
            unsigned int p0 = (unsigned int)f2bf(w0) | ((unsigned int)f2bf(w1) << 16);
            unsigned int p1 = (unsigned int)f2bf(w2) | ((unsigned int)f2bf(w3) << 16);
            *(unsigned int*)&Wt[n * 136 + kk]     = p0;
            *(unsigned int*)&Wt[n * 136 + kk + 2] = p1;
        }
    }

    // agg phase: 16 groups x 16 lanes; each group does 4 nodes
    const int group = t >> 4;
    const int lane  = t & 15;
    const uint4* hv = (const uint4*)hin;
    const float4* bp = (const float4*)bias;
    float4 b0 = bp[lane * 2], b1 = bp[lane * 2 + 1];

    for (int r = 0; r < 4; ++r) {
        const int wid = row0 + r * 16 + group;
        uint4 o = make_uint4(0u, 0u, 0u, 0u);
        if (wid < NN) {
            int c = cnt_g[wid];
            if (c > RAWSTRIDE) c = RAWSTRIDE;
            const float diw = dinv[wid];
            const unsigned short* rrow = raw + (size_t)wid * RAWSTRIDE;
            float acc[8];
            AGG128_BODY(hv, rrow, c, diw, lane, acc)
            acc[0] += b0.x; acc[1] += b0.y; acc[2] += b0.z; acc[3] += b0.w;
            acc[4] += b1.x; acc[5] += b1.y; acc[6] += b1.z; acc[7] += b1.w;
            #pragma unroll
            for (int j = 0; j < 8; ++j) acc[j] = fmaxf(acc[j], 0.f);
            o.x = (unsigned int)f2bf(acc[0]) | ((unsigned int)f2bf(acc[1]) << 16);
            o.y = (unsigned int)f2bf(acc[2]) | ((unsigned int)f2bf(acc[3]) << 16);
            o.z = (unsigned int)f2bf(acc[4]) | ((unsigned int)f2bf(acc[5]) << 16);
            o.w = (unsigned int)f2bf(acc[6]) | ((unsigned int)f2bf(acc[7]) << 16);
        }
        *(uint4*)&Zt[(r * 16 + group) * 136 + lane * 8] = o;
    }
    __syncthreads();

    // MFMA phase: h2 = z1 @ W2
    const int wave = t >> 6;
    const int l64  = t & 63;
    const int m16  = l64 & 15;
    const int quad = l64 >> 4;

    f4v acc[8];
    #pragma unroll
    for (int i = 0; i < 8; ++i) acc[i] = (f4v)(0.0f);

    #pragma unroll
    for (int k0 = 0; k0 < 128; k0 += 32) {
        bf8v afrag = *(const bf8v*)&Zt[(wave * 16 + m16) * 136 + k0 + quad * 8];
        #pragma unroll
        for (int nt = 0; nt < 8; ++nt) {
            bf8v bfrag = *(const bf8v*)&Wt[(nt * 16 + m16) * 136 + k0 + quad * 8];
            acc[nt] = __builtin_amdgcn_mfma_f32_16x16x32_bf16(afrag, bfrag, acc[nt], 0, 0, 0);
        }
    }
    __syncthreads();   // all Zt reads done before aliasing as Dt

    #pragma unroll
    for (int nt = 0; nt < 8; ++nt) {
        #pragma unroll
        for (int r = 0; r < 4; ++r) {
            Zt[(wave * 16 + quad * 4 + r) * 136 + nt * 16 + m16] = f2bf(acc[nt][r]);
        }
    }
    __syncthreads();

    {
        int r = t >> 2;
        int c = t & 3;
        int gr = row0 + r;
        if (gr < NN) {
            const uint4* s = (const uint4*)&Zt[r * 136] + c * 4;
            uint4* d = (uint4*)(out + (size_t)gr * 128) + c * 4;
            d[0] = s[0]; d[1] = s[1]; d[2] = s[2]; d[3] = s[3];
        }
    }
}

// ---------------- fused layer-2 agg + layer-3 GEMM (fp32) ----------------
// Block owns 64 nodes: agg z2 = relu(Â·h2 + b2) into LDS fp32 tile, then fp32 z2@W3 -> h3b.

__global__ __launch_bounds__(256) void aggG3_kernel(const unsigned short* __restrict__ hin,
                                                    const unsigned short* __restrict__ raw,
                                                    const int* __restrict__ cnt_g,
                                                    const float* __restrict__ dinv,
                                                    const float* __restrict__ bias,
                                                    const float* __restrict__ W,
                                                    unsigned short* __restrict__ outh) {
    constexpr int LD = 132;
    __shared__ float Zt[64 * LD];              // z2 tile fp32
    const int t = threadIdx.x;
    const int row0 = blockIdx.x * 64;

    const int group = t >> 4;
    const int lane  = t & 15;
    const uint4* hv = (const uint4*)hin;
    const float4* bp = (const float4*)bias;
    float4 b0 = bp[lane * 2], b1 = bp[lane * 2 + 1];

    for (int r = 0; r < 4; ++r) {
        const int wid = row0 + r * 16 + group;
        float acc[8] = {0.f, 0.f, 0.f, 0.f, 0.f, 0.f, 0.f, 0.f};
        if (wid < NN) {
            int c = cnt_g[wid];
            if (c > RAWSTRIDE) c = RAWSTRIDE;
            const float diw = dinv[wid];
            const unsigned short* rrow = raw + (size_t)wid * RAWSTRIDE;
            AGG128_BODY(hv, rrow, c, diw, lane, acc)
            acc[0] += b0.x; acc[1] += b0.y; acc[2] += b0.z; acc[3] += b0.w;
            acc[4] += b1.x; acc[5] += b1.y; acc[6] += b1.z; acc[7] += b1.w;
            #pragma unroll
            for (int j = 0; j < 8; ++j) acc[j] = fmaxf(acc[j], 0.f);
        }
        float4* zr = (float4*)&Zt[(r * 16 + group) * LD + lane * 8];
        zr[0] = make_float4(acc[0], acc[1], acc[2], acc[3]);
        zr[1] = make_float4(acc[4], acc[5], acc[6], acc[7]);
    }
    __syncthreads();

    // fp32 GEMM: h3 = z2 @ W3  (W3 is [128][64])
    constexpr int CG = 16;
    constexpr int RPT = 4;
    const int cg = t % CG;
    const int rt = t / CG;
    const float4* Wv = (const float4*)W;
    float4 acc[RPT];
    #pragma unroll
    for (int i = 0; i < RPT; ++i) acc[i] = make_float4(0.f, 0.f, 0.f, 0.f);

    for (int k0 = 0; k0 < 128; k0 += 4) {
        float4 w0 = Wv[(k0 + 0) * CG + cg];
        float4 w1 = Wv[(k0 + 1) * CG + cg];
        float4 w2 = Wv[(k0 + 2) * CG + cg];
        float4 w3 = Wv[(k0 + 3) * CG + cg];
        #pragma unroll
        for (int i = 0; i < RPT; ++i) {
            const float* lr = Zt + (rt * RPT + i) * LD;
            float4 a = ((const float4*)lr)[k0 >> 2];
            acc[i].x += a.x * w0.x + a.y * w1.x + a.z * w2.x + a.w * w3.x;
            acc[i].y += a.x * w0.y + a.y * w1.y + a.z * w2.y + a.w * w3.y;
            acc[i].z += a.x * w0.z + a.y * w1.z + a.z * w2.z + a.w * w3.z;
            acc[i].w += a.x * w0.w + a.y * w1.w + a.z * w2.w + a.w * w3.w;
        }
    }

    #pragma unroll
    for (int i = 0; i < RPT; ++i) {
        int gr = row0 + rt * RPT + i;
        if (gr < NN) {
            uint2 o;
            o.x = (unsigned int)f2bf(acc[i].x) | ((unsigned int)f2bf(acc[i].y) << 16);
            o.y = (unsigned int)f2bf(acc[i].z) | ((unsigned int)f2bf(acc[i].w) << 16);
            ((uint2*)(outh + (size_t)gr * 64))[cg] = o;
        }
    }
}

// ---------------- layer-3 aggregation: bf16 gather (128B rows) -> fp32 out ----------------

__global__ __launch_bounds__(256) void agg3_kernel(const unsigned short* __restrict__ hin,
                                                   const unsigned short* __restrict__ raw,
                                                   const int* __restrict__ cnt_g,
                                                   const float* __restrict__ dinv,
                                                   const float* __restrict__ bias,
                                                   float* __restrict__ out) {
    const int t = threadIdx.x;
    const int group = t >> 3;
    const int lane  = t & 7;
    const int wid = blockIdx.x * 32 + group;
    if (wid >= NN) return;

    int c = cnt_g[wid];
    if (c > RAWSTRIDE) c = RAWSTRIDE;
    const float diw = dinv[wid];
    const unsigned short* rrow = raw + (size_t)wid * RAWSTRIDE;
    const uint4* hv = (const uint4*)hin;      // 8 uint4 per 64-feat bf16 row

    float acc[8];
    {   // self loop
        uint4 g = hv[(size_t)wid * 8 + lane];
        float ws = diw * diw;
        acc[0] = ws * bflo(g.x); acc[1] = ws * bfhi(g.x);
        acc[2] = ws * bflo(g.y); acc[3] = ws * bfhi(g.y);
        acc[4] = ws * bflo(g.z); acc[5] = ws * bfhi(g.z);
        acc[6] = ws * bflo(g.w); acc[7] = ws * bfhi(g.w);
    }

    const int cfull = c & ~7;
    uint4 q;
    if (cfull > 0) q = *(const uint4*)(rrow);
    for (int e = 0; e < cfull; e += 8) {
        uint4 qc = q;
        if (e + 8 < cfull) q = *(const uint4*)(rrow + e + 8);
        int c0 = qc.x & 0xFFFFu, c1 = qc.x >> 16;
        int c2 = qc.y & 0xFFFFu, c3 = qc.y >> 16;
        int c4 = qc.z & 0xFFFFu, c5 = qc.z >> 16;
        int c6 = qc.w & 0xFFFFu, c7 = qc.w >> 16;
        uint4 g0 = hv[(size_t)c0 * 8 + lane];
        uint4 g1 = hv[(size_t)c1 * 8 + lane];
        uint4 g2 = hv[(size_t)c2 * 8 + lane];
        uint4 g3 = hv[(size_t)c3 * 8 + lane];
        uint4 g4 = hv[(size_t)c4 * 8 + lane];
        uint4 g5 = hv[(size_t)c5 * 8 + lane];
        uint4 g6 = hv[(size_t)c6 * 8 + lane];
        uint4 g7 = hv[(size_t)c7 * 8 + lane];
        float w0 = diw * dinv[c0], w1 = diw * dinv[c1];
        float w2 = diw * dinv[c2], w3 = diw * dinv[c3];
        float w4 = diw * dinv[c4], w5 = diw * dinv[c5];
        float w6 = diw * dinv[c6], w7 = diw * dinv[c7];
        ACC8(g0, w0) ACC8(g1, w1) ACC8(g2, w2) ACC8(g3, w3)
        ACC8(g4, w4) ACC8(g5, w5) ACC8(g6, w6) ACC8(g7, w7)
    }
    if (c & 7) {
        int e = cfull, rem = c - e;
        uint4 qc = *(const uint4*)(rrow + e);
        int c0 = qc.x & 0xFFFFu, c1 = qc.x >> 16;
        int c2 = qc.y & 0xFFFFu, c3 = qc.y >> 16;
        int c4 = qc.z & 0xFFFFu, c5 = qc.z >> 16;
        int c6 = qc.w & 0xFFFFu, c7 = qc.w >> 16;
        if (rem <= 1) c1 = 0; if (rem <= 2) c2 = 0; if (rem <= 3) c3 = 0;
        if (rem <= 4) c4 = 0; if (rem <= 5) c5 = 0; if (rem <= 6) c6 = 0;
        c7 = 0;
        float w0 = diw * dinv[c0];
        float w1 = (rem > 1) ? diw * dinv[c1] : 0.f;
        float w2 = (rem > 2) ? diw * dinv[c2] : 0.f;
        float w3 = (rem > 3) ? diw * dinv[c3] : 0.f;
        float w4 = (rem > 4) ? diw * dinv[c4] : 0.f;
        float w5 = (rem > 5) ? diw * dinv[c5] : 0.f;
        float w6 = (rem > 6) ? diw * dinv[c6] : 0.f;
        float w7 = 0.f;
        uint4 g0 = hv[(size_t)c0 * 8 + lane];
        uint4 g1 = hv[(size_t)c1 * 8 + lane];
        uint4 g2 = hv[(size_t)c2 * 8 + lane];
        uint4 g3 = hv[(size_t)c3 * 8 + lane];
        uint4 g4 = hv[(size_t)c4 * 8 + lane];
        uint4 g5 = hv[(size_t)c5 * 8 + lane];
        uint4 g6 = hv[(size_t)c6 * 8 + lane];
        uint4 g7 = hv[(size_t)c7 * 8 + lane];
        ACC8(g0, w0) ACC8(g1, w1) ACC8(g2, w2) ACC8(g3, w3)
        ACC8(g4, w4) ACC8(g5, w5) ACC8(g6, w6) ACC8(g7, w7)
    }

    const float4* bp = (const float4*)bias;
    float4 b0 = bp[lane * 2], b1 = bp[lane * 2 + 1];
    acc[0] += b0.x; acc[1] += b0.y; acc[2] += b0.z; acc[3] += b0.w;
    acc[4] += b1.x; acc[5] += b1.y; acc[6] += b1.z; acc[7] += b1.w;

    float4 o0 = make_float4(acc[0], acc[1], acc[2], acc[3]);
    float4 o1 = make_float4(acc[4], acc[5], acc[6], acc[7]);
    ((float4*)(out + (size_t)wid * 64))[lane * 2]     = o0;
    ((float4*)(out + (size_t)wid * 64))[lane * 2 + 1] = o1;
}

// ---------------- launch ----------------

extern "C" void kernel_launch(void* const* d_in, const int* in_sizes, int n_in,
                              void* d_out, int out_size, void* d_ws, size_t ws_size,
                              hipStream_t stream) {
    const float* x  = (const float*)d_in[0];
    const int*   ei = (const int*)d_in[1];     // [2, NE], row0=src, row1=dst
    const float* W1 = (const float*)d_in[2];
    const float* b1 = (const float*)d_in[3];
    const float* W2 = (const float*)d_in[4];
    const float* b2 = (const float*)d_in[5];
    const float* W3 = (const float*)d_in[6];
    const float* b3 = (const float*)d_in[7];
    float* out = (float*)d_out;

    // Workspace map:
    //   cnt_g   @ 0x0000000  200,000 B
    //   gcursor @ 0x0040000  784 B       (memset only this)
    //   dinv    @ 0x0048000  200,000 B
    //   bst     @ 0x0080000  3,612,672 B
    //   raw     @ 0x0400000  9,600,000 B
    //   hb      @ 0x0E00000  12,800,000 B   (gemm1 out)
    //   h2b     @ 0x1B00000  12,800,000 B   (aggW2 out)
    //   h3b     @ 0x2800000   6,400,000 B   (aggG3 out)   (~48 MB total)
    char* w = (char*)d_ws;
    int*   cnt_g   = (int*)  (w + 0x0000000);
    int*   gcursor = (int*)  (w + 0x0040000);
    float* dinv    = (float*)(w + 0x0048000);
    unsigned int*   bst = (unsigned int*)  (w + 0x0080000);
    unsigned short* raw = (unsigned short*)(w + 0x0400000);
    unsigned short* hb  = (unsigned short*)(w + 0x0E00000);
    unsigned short* h2b = (unsigned short*)(w + 0x1B00000);
    unsigned short* h3b = (unsigned short*)(w + 0x2800000);

    const int* src = ei;
    const int* dst = ei + NE;

    hipMemsetAsync(gcursor, 0, NBUCK * sizeof(int), stream);
    // fused: CSR binning + layer-1 GEMM (independent)
    bin_g1_kernel<<<NBBIN + G1B, 256, 0, stream>>>(src, dst, gcursor, bst, x, W1, hb);
    sortb_kernel<<<NBUCK, 512, 0, stream>>>(gcursor, bst, cnt_g, dinv, raw);
    // fused layer-1 agg + layer-2 GEMM
    aggW2_kernel<<<G1B, 256, 0, stream>>>(hb, raw, cnt_g, dinv, b1, W2, h2b);
    // fused layer-2 agg + layer-3 GEMM (fp32)
    aggG3_kernel<<<G1B, 256, 0, stream>>>(h2b, raw, cnt_g, dinv, b2, W3, h3b);
    // final aggregation straight to output
    agg3_kernel<<<(NN + 31) / 32, 256, 0, stream>>>(h3b, raw, cnt_g, dinv, b3, out);
}